// Round 4
// baseline (333.945 us; speedup 1.0000x reference)
//
#include <hip/hip_runtime.h>
#include <hip/hip_cooperative_groups.h>
#include <math.h>

namespace cg = cooperative_groups;

typedef _Float16 h16;
typedef __attribute__((ext_vector_type(4))) _Float16 h16x4;
typedef __attribute__((ext_vector_type(8))) _Float16 h16x8;
typedef __attribute__((ext_vector_type(4))) float f32x4;
typedef unsigned long long u64t;
typedef unsigned int u32t;
typedef unsigned char u8t;

struct Params {
    const float *Wq, *Wk, *Wv, *Ws2, *Ws1, *bo, *bs1;
    const float *cw1, *cb1, *cw2, *cb2;
    const float *Xq, *Xk, *Xv, *Wo, *bq, *bk, *bv, *bs2;
    const float *dist; const int *mask;
    h16 *WT, *qb, *kb, *vbT, *OB, *h1, *WbigT, *XHw, *XHx;
    float *bcombP, *tthr, *fLUT, *outF;
};

// ---------------------------------------------------------------------------
// hgemm half-block: 32x64 tile, 256 threads (tid), k-step 64, double-buffered.
// ---------------------------------------------------------------------------
__device__ __forceinline__ void hgemm_half(
    int tid, u8t* lds, int task,
    const h16* __restrict__ A, const h16* __restrict__ Bt,
    const float* __restrict__ bias, void* __restrict__ outv,
    int K, int nbp, int out16relu)
{
    typedef h16 tA[32][72];
    typedef h16 tB[64][72];
    tA* As = (tA*)lds;
    tB* Bs = (tB*)(lds + 9216);
    const int w = tid >> 6, ln = tid & 63;
    const int Q = ln >> 4, n = ln & 15;
    const int row0 = (task >> 2) * 32, col0 = (task & 3) * 64;
    const int r16 = (w & 1) * 16, c32 = (w >> 1) * 32;
    const int asr = tid >> 3, asc = (tid & 7) * 8;
    const int bsr = tid >> 2, bsc = (tid & 3) * 16;

    auto ldA = [&](int k0) -> h16x8 {
        return *(const h16x8*)(A + (size_t)(row0 + asr) * K + k0 + asc);
    };
    auto ldB0 = [&](int k0) -> h16x8 {
        return *(const h16x8*)(Bt + (size_t)(col0 + bsr) * K + k0 + bsc);
    };
    auto ldB1 = [&](int k0) -> h16x8 {
        return *(const h16x8*)(Bt + (size_t)(col0 + bsr) * K + k0 + bsc + 8);
    };

    {
        h16x8 a0 = ldA(0), b0 = ldB0(0), b1 = ldB1(0);
        *(h16x8*)&As[0][asr][asc] = a0;
        *(h16x8*)&Bs[0][bsr][bsc] = b0;
        *(h16x8*)&Bs[0][bsr][bsc + 8] = b1;
    }
    __syncthreads();

    f32x4 acc2[2];
    acc2[0] = (f32x4){0.f, 0.f, 0.f, 0.f};
    acc2[1] = (f32x4){0.f, 0.f, 0.f, 0.f};
    const int iters = K >> 6;

    for (int it = 0; it < iters; ++it) {
        const int cur = it & 1;
        h16x8 arN, brN0, brN1;
        if (it + 1 < iters) {
            arN = ldA(64 * (it + 1));
            brN0 = ldB0(64 * (it + 1));
            brN1 = ldB1(64 * (it + 1));
        }
        #pragma unroll
        for (int kh = 0; kh < 2; ++kh) {
            h16x8 af = *(const h16x8*)&As[cur][r16 + n][kh * 32 + Q * 8];
            #pragma unroll
            for (int cg2 = 0; cg2 < 2; ++cg2) {
                h16x8 bf = *(const h16x8*)&Bs[cur][c32 + cg2 * 16 + n][kh * 32 + Q * 8];
                acc2[cg2] = __builtin_amdgcn_mfma_f32_16x16x32_f16(af, bf, acc2[cg2], 0, 0, 0);
            }
        }
        if (it + 1 < iters) {
            *(h16x8*)&As[cur ^ 1][asr][asc] = arN;
            *(h16x8*)&Bs[cur ^ 1][bsr][bsc] = brN0;
            *(h16x8*)&Bs[cur ^ 1][bsr][bsc + 8] = brN1;
        }
        __syncthreads();
    }

    #pragma unroll
    for (int cg2 = 0; cg2 < 2; ++cg2) {
        const int col = col0 + c32 + cg2 * 16 + n;
        float bv = bias[col];
        for (int pp = 1; pp < nbp; ++pp) bv += bias[pp * 256 + col];
        #pragma unroll
        for (int r = 0; r < 4; ++r) {
            const int row = row0 + r16 + 4 * Q + r;
            if (out16relu)
                ((h16*)outv)[(size_t)row * 256 + col] = (h16)fmaxf(acc2[cg2][r] + bv, 0.f);
            else
                ((float*)outv)[(size_t)row * 256 + col] = acc2[cg2][r] + bv;
        }
    }
}

// ---------------------------------------------------------------------------
// mega_k: all 5 phases in one cooperative kernel, grid.sync() between.
// 256 blocks x 512 threads, 1 block/CU guaranteed co-resident.
// ---------------------------------------------------------------------------
__global__ __launch_bounds__(512, 2) void mega_k(Params p)
{
    __shared__ __align__(16) u8t smem[55296];
    cg::grid_group grid = cg::this_grid();
    const int bid = blockIdx.x;
    const int t = threadIdx.x;
    const int w8 = t >> 6, lane = t & 63;

    // ================= phase 0: prep (wave-synchronous tasks) =================
    {
        const int gw = bid * 8 + w8;
        for (int task = gw; task < 6785; task += 2048) {
            if (task < 448) {
                // 32x32 transpose f32->f16, wave-private LDS tile [32][33]
                float* T = (float*)(smem + w8 * 4224);
                const int z = task >> 6, idx = task & 63;
                const float* in = (z == 0) ? p.Wq : (z == 1) ? p.Wk :
                                  (z == 2) ? p.Wv : (z == 3) ? p.Ws2 :
                                  (p.Ws1 + (size_t)(z - 4) * 65536);
                h16* out = p.WT + (size_t)z * 65536;
                const int r0 = (idx >> 3) * 32, c0 = (idx & 7) * 32;
                const int row = lane >> 1, ch = (lane & 1) * 16;
                const float* ip = in + (size_t)(r0 + row) * 256 + c0 + ch;
                #pragma unroll
                for (int j = 0; j < 4; ++j) {
                    float4 v = *(const float4*)(ip + 4 * j);
                    float* tr = T + row * 33 + ch + 4 * j;
                    tr[0] = v.x; tr[1] = v.y; tr[2] = v.z; tr[3] = v.w;
                }
                __builtin_amdgcn_wave_barrier();
                asm volatile("s_waitcnt lgkmcnt(0)" ::: "memory");
                __builtin_amdgcn_sched_barrier(0);
                h16 ov[16] __attribute__((aligned(16)));
                #pragma unroll
                for (int j = 0; j < 16; ++j) ov[j] = (h16)T[(ch + j) * 33 + row];
                h16* op = out + (size_t)(c0 + row) * 256 + r0 + ch;
                *(h16x8*)op = *(h16x8*)&ov[0];
                *(h16x8*)(op + 8) = *(h16x8*)&ov[8];
                __builtin_amdgcn_wave_barrier();
                asm volatile("s_waitcnt lgkmcnt(0)" ::: "memory");
            } else if (task < 512) {
                // bcomb partials: 64 wave-tasks (16 row-chunks x 4 col-quarters)
                const int wt = task - 448, chunk = wt >> 2;
                const int col = (wt & 3) * 64 + lane;
                float acc = (chunk == 0) ? p.bs1[col] : 0.f;
                const int r0 = chunk * 48;
                #pragma unroll 4
                for (int r = r0; r < r0 + 48; ++r)
                    acc = fmaf(p.bo[r & 255], p.Ws1[(size_t)r * 256 + col], acc);
                p.bcombP[chunk * 256 + col] = acc;
            } else if (task == 512) {
                // piecewise-linear dist-conv LUT (9 intervals x 8 heads)
                const float INVS = 0.17677669529663687f;
                float tv[8]; int zu[8];
                #pragma unroll
                for (int u = 0; u < 8; ++u) {
                    const float w = p.cw1[u];
                    zu[u] = (w == 0.f) ? 1 : 0;
                    tv[u] = zu[u] ? 3.0e38f : (-p.cb1[u] / w);
                }
                if (lane < 8) p.tthr[lane] = tv[lane];
                #pragma unroll
                for (int ee = 0; ee < 2; ++ee) {
                    const int e = lane + 64 * ee;
                    if (e < 72) {
                        const int h = e & 7, jj = e >> 3;
                        int rank[8];
                        #pragma unroll
                        for (int u = 0; u < 8; ++u) {
                            int rk = 0;
                            #pragma unroll
                            for (int v = 0; v < 8; ++v)
                                rk += ((tv[v] < tv[u]) || (tv[v] == tv[u] && v < u)) ? 1 : 0;
                            rank[u] = rk;
                        }
                        float slope = 0.f, inter = p.cb2[h];
                        #pragma unroll
                        for (int u = 0; u < 8; ++u) {
                            const float c2 = p.cw2[h * 8 + u];
                            if (zu[u]) {
                                inter += c2 * fmaxf(p.cb1[u], 0.f);
                            } else {
                                const bool act = (p.cw1[u] > 0.f) ? (rank[u] < jj) : (rank[u] >= jj);
                                if (act) {
                                    slope = fmaf(c2, p.cw1[u], slope);
                                    inter = fmaf(c2, p.cb1[u], inter);
                                }
                            }
                        }
                        float2 ev; ev.x = INVS * slope; ev.y = INVS * inter;
                        ((float2*)p.fLUT)[jj * 8 + h] = ev;
                    }
                }
            } else {
                // f32->f16 conversion: [Xq|Xk|Xv] -> XHx (aliases OB), Wo -> XHw
                const size_t basei = (size_t)(task - 513) * 512 + (size_t)lane * 8;
                const float* src; h16* dst;
                if (basei < 3145728) {
                    const int z = (int)(basei >> 20);
                    src = ((z == 0) ? p.Xq : (z == 1) ? p.Xk : p.Xv) + (basei & 1048575);
                    dst = p.XHx + basei;
                } else {
                    src = p.Wo + (basei - 3145728);
                    dst = p.XHw + (basei - 3145728);
                }
                float4 f0 = *(const float4*)src;
                float4 f1 = *(const float4*)(src + 4);
                h16x8 hv;
                hv[0] = (h16)f0.x; hv[1] = (h16)f0.y; hv[2] = (h16)f0.z; hv[3] = (h16)f0.w;
                hv[4] = (h16)f1.x; hv[5] = (h16)f1.y; hv[6] = (h16)f1.z; hv[7] = (h16)f1.w;
                *(h16x8*)dst = hv;
            }
        }
    }
    grid.sync();

    // ================= phase 1: qkvw (two 256-thread halves) =================
    {
        const int half = t >> 8, tid = t & 255;
        u8t* lds = smem + half * 20480;
        typedef h16 qtile[64][40];
        qtile* As = (qtile*)lds;
        qtile* Bs = (qtile*)(lds + 10240);
        const int wq = tid >> 6, lq = tid & 63;
        const int Q = lq >> 4, n = lq & 15;
        const int sr = tid >> 2, sc = (tid & 3) * 8;

        for (int base = 0; base < 816; base += 512) {
            const int task = base + bid * 2 + half;
            const bool valid = task < 816;
            int mode = -1, row0, col0, sgm = 0;
            const h16 *A = p.XHx, *Bt = p.WT; const float* bias = p.bq;
            if (valid) {
                if (task < 768) {
                    const int z = task >> 8, r = task & 255;
                    row0 = (r & 63) * 64; col0 = (r >> 6) * 64;
                    A = p.XHx + (size_t)z * 1048576;
                    Bt = p.WT + (size_t)z * 65536;
                    bias = (z == 0) ? p.bq : (z == 1) ? p.bk : p.bv;
                    mode = z;
                } else {
                    const int r = task - 768;
                    sgm = r >> 4; const int tt2 = r & 15;
                    row0 = (tt2 >> 2) * 64; col0 = (tt2 & 3) * 64;
                    A = p.XHw; Bt = p.WT + (size_t)(4 + sgm) * 65536; mode = 3;
                }
            } else {
                const int r = task & 255;
                row0 = (r & 63) * 64; col0 = (r >> 6) * 64;
            }

            auto ldA = [&](int k0) -> h16x8 {
                return *(const h16x8*)(A + (size_t)(row0 + sr) * 256 + k0 + sc);
            };
            auto ldB = [&](int k0) -> h16x8 {
                return *(const h16x8*)(Bt + (size_t)(col0 + sr) * 256 + k0 + sc);
            };

            {
                h16x8 a0 = ldA(0), b0 = ldB(0);
                *(h16x8*)&As[0][sr][sc] = a0;
                *(h16x8*)&Bs[0][sr][sc] = b0;
            }
            __syncthreads();

            f32x4 acc4[4];
            #pragma unroll
            for (int c = 0; c < 4; ++c) acc4[c] = (f32x4){0.f, 0.f, 0.f, 0.f};

            for (int it = 0; it < 8; ++it) {
                const int cur = it & 1;
                h16x8 arN, brN;
                if (it < 7) { arN = ldA(32 * (it + 1)); brN = ldB(32 * (it + 1)); }
                h16x8 af = *(const h16x8*)&As[cur][wq * 16 + n][Q * 8];
                #pragma unroll
                for (int cg2 = 0; cg2 < 4; ++cg2) {
                    h16x8 bf = *(const h16x8*)&Bs[cur][cg2 * 16 + n][Q * 8];
                    acc4[cg2] = __builtin_amdgcn_mfma_f32_16x16x32_f16(af, bf, acc4[cg2], 0, 0, 0);
                }
                if (it < 7) {
                    *(h16x8*)&As[cur ^ 1][sr][sc] = arN;
                    *(h16x8*)&Bs[cur ^ 1][sr][sc] = brN;
                }
                __syncthreads();
            }

            if (mode == 0 || mode == 1) {
                h16* out = mode ? p.kb : p.qb;
                #pragma unroll
                for (int cg2 = 0; cg2 < 4; ++cg2) {
                    const float bvv = bias[col0 + cg2 * 16 + n];
                    #pragma unroll
                    for (int r = 0; r < 4; ++r)
                        out[(size_t)(row0 + wq * 16 + 4 * Q + r) * 256 + col0 + cg2 * 16 + n] =
                            (h16)(acc4[cg2][r] + bvv);
                }
            } else if (mode == 2) {
                const int bb = row0 >> 9;
                #pragma unroll
                for (int cg2 = 0; cg2 < 4; ++cg2) {
                    const float bvv = bias[col0 + cg2 * 16 + n];
                    const int col = col0 + cg2 * 16 + n;
                    #pragma unroll
                    for (int r = 0; r < 4; ++r) {
                        const int m = row0 + wq * 16 + 4 * Q + r;
                        p.vbT[((size_t)(bb * 256 + col)) * 512 + (m & 511)] =
                            (h16)(acc4[cg2][r] + bvv);
                    }
                }
            } else if (mode == 3) {
                #pragma unroll
                for (int cg2 = 0; cg2 < 4; ++cg2) {
                    const int col = col0 + cg2 * 16 + n;
                    #pragma unroll
                    for (int r = 0; r < 4; ++r)
                        p.WbigT[(size_t)col * 768 + sgm * 256 + row0 + wq * 16 + 4 * Q + r] =
                            (h16)acc4[cg2][r];
                }
            }
        }
    }
    grid.sync();

    // ================= phase 2: attention =================
    {
        const int b = bid >> 5, q0 = (bid & 31) * 16;
        const int w = w8, Q = lane >> 4, n = lane & 15;
        const int h = w;
        h16 (*Dd)[16][72] = (h16(*)[16][72])(smem);            // [2][16][72]
        u8t (*Cd)[16][72] = (u8t(*)[16][72])(smem + 4608);     // [2][16][72]
        h16 (*Sx)[16][72] = (h16(*)[16][72])(smem + 6912);     // [8][16][72]
        float2 (*lutS)[9] = (float2(*)[9])(smem + 25344);      // [8][9]

        float th[8];
        #pragma unroll
        for (int u = 0; u < 8; ++u) th[u] = p.tthr[u];
        if (t < 72) lutS[t & 7][t >> 3] = ((const float2*)p.fLUT)[t];

        const h16x8 aq =
            *(const h16x8*)(p.qb + ((size_t)(b * 512 + q0 + n)) * 256 + h * 32 + Q * 8);

        const f32x4 z4 = {0.f, 0.f, 0.f, 0.f};
        f32x4 acc[3][2];
        #pragma unroll
        for (int s = 0; s < 3; ++s) { acc[s][0] = z4; acc[s][1] = z4; }
        float mprev = -3e38f;
        float lsum[3] = {0.f, 0.f, 0.f};

        const int scol = lane;

        auto stage = [&](int buf, int kkb, const float* dp, const int* mp) {
            #pragma unroll
            for (int i = 0; i < 2; ++i) {
                const int row = w + 8 * i;
                const float d = dp[i];
                int idx = 0;
                #pragma unroll
                for (int u = 0; u < 8; ++u) idx += (d > th[u]) ? 1 : 0;
                const bool fr = ((q0 + row) == 0) || ((kkb + scol) == 0);
                const bool keep = (mp[i] != 0);
                const u32t code = (keep && (fr || d < 0.3f) ? 1u : 0u)
                                | (keep && (fr || d < 0.7f) ? 2u : 0u)
                                | (keep ? 4u : 0u)
                                | ((u32t)idx << 3);
                Cd[buf][row][scol] = (u8t)code;
                Dd[buf][row][scol] = (h16)d;
            }
        };

        float dv[2]; int mkv[2];
        #pragma unroll
        for (int i = 0; i < 2; ++i) {
            const size_t off = ((size_t)(b * 512 + q0 + w + 8 * i)) * 512 + scol;
            dv[i] = p.dist[off]; mkv[i] = p.mask[off];
        }
        h16x8 kf[4], vf[4];
        #pragma unroll
        for (int cg2 = 0; cg2 < 4; ++cg2)
            kf[cg2] = *(const h16x8*)(p.kb + ((size_t)(b * 512 + cg2 * 16 + n)) * 256 + h * 32 + Q * 8);
        #pragma unroll
        for (int nh = 0; nh < 2; ++nh)
            #pragma unroll
            for (int k2 = 0; k2 < 2; ++k2)
                vf[nh * 2 + k2] = *(const h16x8*)(
                    p.vbT + ((size_t)((b * 8 + h) * 32 + nh * 16 + n)) * 512 + k2 * 32 + Q * 8);
        stage(0, 0, dv, mkv);
        __syncthreads();

        for (int kc = 0; kc < 8; ++kc) {
            const int cur = kc & 1, kk0 = kc * 64;

            float dN[2]; int mkN[2]; h16x8 kfN[4], vfN[4];
            if (kc < 7) {
                const int kn = kk0 + 64;
                #pragma unroll
                for (int i = 0; i < 2; ++i) {
                    const size_t off = ((size_t)(b * 512 + q0 + w + 8 * i)) * 512 + kn + scol;
                    dN[i] = p.dist[off]; mkN[i] = p.mask[off];
                }
                #pragma unroll
                for (int cg2 = 0; cg2 < 4; ++cg2)
                    kfN[cg2] = *(const h16x8*)(
                        p.kb + ((size_t)(b * 512 + kn + cg2 * 16 + n)) * 256 + h * 32 + Q * 8);
                #pragma unroll
                for (int nh = 0; nh < 2; ++nh)
                    #pragma unroll
                    for (int k2 = 0; k2 < 2; ++k2)
                        vfN[nh * 2 + k2] = *(const h16x8*)(
                            p.vbT + ((size_t)((b * 8 + h) * 32 + nh * 16 + n)) * 512
                                + kn + k2 * 32 + Q * 8);
            }

            f32x4 s4[4];
            #pragma unroll
            for (int cg2 = 0; cg2 < 4; ++cg2)
                s4[cg2] = __builtin_amdgcn_mfma_f32_16x16x32_f16(aq, kf[cg2], z4, 0, 0, 0);

            #pragma unroll
            for (int cg2 = 0; cg2 < 4; ++cg2)
                #pragma unroll
                for (int r = 0; r < 4; ++r)
                    Sx[w][4 * Q + r][cg2 * 16 + n] = (h16)s4[cg2][r];
            __builtin_amdgcn_wave_barrier();

            const u64t cd0 = *(const u64t*)&Cd[cur][n][Q * 8];
            const u64t cd1 = *(const u64t*)&Cd[cur][n][32 + Q * 8];
            const h16x8 dd0 = *(const h16x8*)&Dd[cur][n][Q * 8];
            const h16x8 dd1 = *(const h16x8*)&Dd[cur][n][32 + Q * 8];
            float sv[16];
            {
                h16x8 s0 = *(const h16x8*)&Sx[w][n][Q * 8];
                h16x8 s1 = *(const h16x8*)&Sx[w][n][32 + Q * 8];
                #pragma unroll
                for (int i = 0; i < 16; ++i) {
                    const u32t byte = (u32t)((i < 8 ? cd0 : cd1) >> (8 * (i & 7))) & 0xFFu;
                    const int idx = (int)(byte >> 3);
                    const float2 se = lutS[w][idx];
                    const float dfi = (float)((i < 8) ? dd0[i & 7] : dd1[i & 7]);
                    const float f = fmaf(dfi, se.x, se.y);
                    sv[i] = (float)((i < 8) ? s0[i & 7] : s1[i & 7]) * f;
                }
            }
            float cm = -3e38f;
            #pragma unroll
            for (int i = 0; i < 16; ++i) {
                const u32t cc = (u32t)((i < 8 ? cd0 : cd1) >> (8 * (i & 7))) & 7u;
                cm = fmaxf(cm, (cc & 4u) ? sv[i] : -3e38f);
            }
            cm = fmaxf(cm, __shfl_xor(cm, 16));
            cm = fmaxf(cm, __shfl_xor(cm, 32));
            const float mnew = fmaxf(mprev, cm);
            const float alphaA = __expf(mprev - mnew);
            mprev = mnew;

            #pragma unroll
            for (int r = 0; r < 4; ++r) {
                const float aR = __shfl(alphaA, 4 * Q + r);
                #pragma unroll
                for (int s = 0; s < 3; ++s) { acc[s][0][r] *= aR; acc[s][1][r] *= aR; }
            }

            h16x8 pf[3][2];
            float l0 = 0.f, l1 = 0.f, l2 = 0.f;
            #pragma unroll
            for (int i = 0; i < 16; ++i) {
                const u32t cc = (u32t)((i < 8 ? cd0 : cd1) >> (8 * (i & 7))) & 7u;
                const float e = __expf(sv[i] - mnew);
                const float p0 = (cc & 1u) ? e : 0.f;
                const float p1 = (cc & 2u) ? e : 0.f;
                const float p2 = (cc & 4u) ? e : 0.f;
                l0 += p0; l1 += p1; l2 += p2;
                pf[0][i >> 3][i & 7] = (h16)p0;
                pf[1][i >> 3][i & 7] = (h16)p1;
                pf[2][i >> 3][i & 7] = (h16)p2;
            }
            lsum[0] = lsum[0] * alphaA + l0;
            lsum[1] = lsum[1] * alphaA + l1;
            lsum[2] = lsum[2] * alphaA + l2;

            #pragma unroll
            for (int k2 = 0; k2 < 2; ++k2)
                #pragma unroll
                for (int nh = 0; nh < 2; ++nh)
                    #pragma unroll
                    for (int s = 0; s < 3; ++s)
                        acc[s][nh] = __builtin_amdgcn_mfma_f32_16x16x32_f16(
                            pf[s][k2], vf[nh * 2 + k2], acc[s][nh], 0, 0, 0);

            if (kc < 7) {
                stage(cur ^ 1, kk0 + 64, dN, mkN);
                #pragma unroll
                for (int i = 0; i < 4; ++i) { kf[i] = kfN[i]; vf[i] = vfN[i]; }
            }
            __syncthreads();
        }

        float lrow[3];
        #pragma unroll
        for (int s = 0; s < 3; ++s) {
            float lv = lsum[s];
            lv += __shfl_xor(lv, 16);
            lv += __shfl_xor(lv, 32);
            lrow[s] = lv;
        }
        #pragma unroll
        for (int s = 0; s < 3; ++s) {
            #pragma unroll
            for (int r = 0; r < 4; ++r) {
                const float il = 1.0f / __shfl(lrow[s], 4 * Q + r);
                const size_t row = (size_t)(b * 512 + q0 + 4 * Q + r);
                h16* op = p.OB + row * 768 + s * 256 + h * 32 + n;
                op[0]  = (h16)(acc[s][0][r] * il);
                op[16] = (h16)(acc[s][1][r] * il);
            }
        }
    }
    grid.sync();

    // ================= phase 3: h1 = relu(OB @ Wbig + bcomb) =================
    {
        const int half = t >> 8, tid = t & 255;
        u8t* lds = smem + half * 27648;
        hgemm_half(tid, lds, bid * 2 + half, p.OB, p.WbigT, p.bcombP, p.h1, 768, 16, 1);
    }
    grid.sync();

    // ================= phase 4: out = h1 @ Ws2 + bs2 =================
    {
        const int half = t >> 8, tid = t & 255;
        u8t* lds = smem + half * 27648;
        hgemm_half(tid, lds, bid * 2 + half, p.h1, p.WT + 3 * 65536, p.bs2, p.outF, 256, 1, 0);
    }
}

// ===========================================================================
// Fallback path: round-3 standalone kernels (used only if the cooperative
// launch is rejected by the runtime).
// ===========================================================================
__global__ __launch_bounds__(256) void prep_k(
    const float* __restrict__ Wq, const float* __restrict__ Wk,
    const float* __restrict__ Wv, const float* __restrict__ Ws2,
    const float* __restrict__ Ws1, const float* __restrict__ bo,
    const float* __restrict__ bs1,
    const float* __restrict__ cw1, const float* __restrict__ cb1,
    const float* __restrict__ cw2, const float* __restrict__ cb2,
    const float* __restrict__ Xq, const float* __restrict__ Xk,
    const float* __restrict__ Xv, const float* __restrict__ Wo,
    h16* __restrict__ WT, float* __restrict__ bcombP,
    float* __restrict__ tthr, float* __restrict__ fLUT,
    h16* __restrict__ XHx, h16* __restrict__ XHw)
{
    const int bid = blockIdx.x;
    __shared__ float T[32][33];
    if (bid < 448) {
        const int z = bid >> 6, idx = bid & 63;
        const float* in = (z == 0) ? Wq : (z == 1) ? Wk : (z == 2) ? Wv :
                          (z == 3) ? Ws2 : (Ws1 + (size_t)(z - 4) * 65536);
        h16* out = WT + (size_t)z * 65536;
        const int t = threadIdx.x, tx = t & 31, ty = t >> 5;
        const int r0 = (idx >> 3) * 32, c0 = (idx & 7) * 32;
        #pragma unroll
        for (int i = 0; i < 4; ++i)
            T[ty + i * 8][tx] = in[(size_t)(r0 + ty + i * 8) * 256 + c0 + tx];
        __syncthreads();
        #pragma unroll
        for (int i = 0; i < 4; ++i)
            out[(size_t)(c0 + ty + i * 8) * 256 + r0 + tx] = (h16)T[tx][ty + i * 8];
    } else if (bid < 464) {
        const int z = bid - 448;
        const int j = threadIdx.x;
        float acc = (z == 0) ? bs1[j] : 0.f;
        const int r0 = z * 48;
        #pragma unroll 4
        for (int r = r0; r < r0 + 48; ++r)
            acc = fmaf(bo[r & 255], Ws1[(size_t)r * 256 + j], acc);
        bcombP[z * 256 + j] = acc;
    } else if (bid == 464) {
        const int t = threadIdx.x;
        const float INVS = 0.17677669529663687f;
        float tv[8]; int zu[8];
        #pragma unroll
        for (int u = 0; u < 8; ++u) {
            const float w = cw1[u];
            zu[u] = (w == 0.f) ? 1 : 0;
            tv[u] = zu[u] ? 3.0e38f : (-cb1[u] / w);
        }
        if (t < 8) tthr[t] = tv[t];
        if (t < 72) {
            const int h = t & 7, jj = t >> 3;
            int rank[8];
            #pragma unroll
            for (int u = 0; u < 8; ++u) {
                int rk = 0;
                #pragma unroll
                for (int v = 0; v < 8; ++v)
                    rk += ((tv[v] < tv[u]) || (tv[v] == tv[u] && v < u)) ? 1 : 0;
                rank[u] = rk;
            }
            float slope = 0.f, inter = cb2[h];
            #pragma unroll
            for (int u = 0; u < 8; ++u) {
                const float c2 = cw2[h * 8 + u];
                if (zu[u]) {
                    inter += c2 * fmaxf(cb1[u], 0.f);
                } else {
                    const bool act = (cw1[u] > 0.f) ? (rank[u] < jj) : (rank[u] >= jj);
                    if (act) {
                        slope = fmaf(c2, cw1[u], slope);
                        inter = fmaf(c2, cb1[u], inter);
                    }
                }
            }
            float2 e; e.x = INVS * slope; e.y = INVS * inter;
            ((float2*)fLUT)[jj * 8 + h] = e;
        }
    } else {
        const size_t idx = (size_t)(bid - 465) * 2048 + (size_t)threadIdx.x * 8;
        const float* src; h16* dst;
        if (idx < 3145728) {
            const int z = (int)(idx >> 20);
            src = ((z == 0) ? Xq : (z == 1) ? Xk : Xv) + (idx & 1048575);
            dst = XHx + idx;
        } else {
            src = Wo + (idx - 3145728);
            dst = XHw + (idx - 3145728);
        }
        float4 f0 = *(const float4*)src;
        float4 f1 = *(const float4*)(src + 4);
        h16x8 hv;
        hv[0] = (h16)f0.x; hv[1] = (h16)f0.y; hv[2] = (h16)f0.z; hv[3] = (h16)f0.w;
        hv[4] = (h16)f1.x; hv[5] = (h16)f1.y; hv[6] = (h16)f1.z; hv[7] = (h16)f1.w;
        *(h16x8*)dst = hv;
    }
}

__global__ __launch_bounds__(256) void qkvw_k(
    const h16* __restrict__ XHx, const h16* __restrict__ XHw,
    const h16* __restrict__ WT,
    const float* __restrict__ bq, const float* __restrict__ bk,
    const float* __restrict__ bv,
    h16* __restrict__ qb, h16* __restrict__ kb, h16* __restrict__ vbT,
    h16* __restrict__ WbigT)
{
    const int bid = blockIdx.x;
    const h16* A; const h16* Bt; const float* bias = nullptr;
    int mode, row0, col0, sgm = 0;
    if (bid < 768) {
        const int z = bid >> 8, r = bid & 255;
        row0 = (r & 63) * 64; col0 = (r >> 6) * 64;
        A = XHx + (size_t)z * 1048576;
        Bt = WT + (size_t)z * 65536;
        bias = (z == 0) ? bq : (z == 1) ? bk : bv;
        mode = z;
    } else {
        const int r = bid - 768;
        sgm = r >> 4; const int tt = r & 15;
        row0 = (tt >> 2) * 64; col0 = (tt & 3) * 64;
        A = XHw; Bt = WT + (size_t)(4 + sgm) * 65536; mode = 3;
    }

    __shared__ __align__(16) h16 As[2][64][40];
    __shared__ __align__(16) h16 Bs[2][64][40];
    const int t = threadIdx.x, w = t >> 6, lane = t & 63;
    const int Q = lane >> 4, n = lane & 15;
    const int sr = t >> 2, sc = (t & 3) * 8;

    auto ldA = [&](int k0) -> h16x8 {
        return *(const h16x8*)(A + (size_t)(row0 + sr) * 256 + k0 + sc);
    };
    auto ldB = [&](int k0) -> h16x8 {
        return *(const h16x8*)(Bt + (size_t)(col0 + sr) * 256 + k0 + sc);
    };

    {
        h16x8 a0 = ldA(0), b0 = ldB(0);
        *(h16x8*)&As[0][sr][sc] = a0;
        *(h16x8*)&Bs[0][sr][sc] = b0;
    }
    __syncthreads();

    f32x4 acc4[4];
    #pragma unroll
    for (int c = 0; c < 4; ++c) acc4[c] = (f32x4){0.f, 0.f, 0.f, 0.f};

    for (int it = 0; it < 8; ++it) {
        const int cur = it & 1;
        h16x8 arN, brN;
        if (it < 7) { arN = ldA(32 * (it + 1)); brN = ldB(32 * (it + 1)); }
        h16x8 af = *(const h16x8*)&As[cur][w * 16 + n][Q * 8];
        #pragma unroll
        for (int cg2 = 0; cg2 < 4; ++cg2) {
            h16x8 bf = *(const h16x8*)&Bs[cur][cg2 * 16 + n][Q * 8];
            acc4[cg2] = __builtin_amdgcn_mfma_f32_16x16x32_f16(af, bf, acc4[cg2], 0, 0, 0);
        }
        if (it < 7) {
            *(h16x8*)&As[cur ^ 1][sr][sc] = arN;
            *(h16x8*)&Bs[cur ^ 1][sr][sc] = brN;
        }
        __syncthreads();
    }

    if (mode < 2) {
        h16* out = mode ? kb : qb;
        #pragma unroll
        for (int cg2 = 0; cg2 < 4; ++cg2) {
            const float bvv = bias[col0 + cg2 * 16 + n];
            #pragma unroll
            for (int r = 0; r < 4; ++r)
                out[(size_t)(row0 + w * 16 + 4 * Q + r) * 256 + col0 + cg2 * 16 + n] =
                    (h16)(acc4[cg2][r] + bvv);
        }
    } else if (mode == 2) {
        const int bb = row0 >> 9;
        #pragma unroll
        for (int cg2 = 0; cg2 < 4; ++cg2) {
            const float bvv = bias[col0 + cg2 * 16 + n];
            const int col = col0 + cg2 * 16 + n;
            #pragma unroll
            for (int r = 0; r < 4; ++r) {
                const int m = row0 + w * 16 + 4 * Q + r;
                vbT[((size_t)(bb * 256 + col)) * 512 + (m & 511)] = (h16)(acc4[cg2][r] + bvv);
            }
        }
    } else {
        #pragma unroll
        for (int cg2 = 0; cg2 < 4; ++cg2) {
            const int col = col0 + cg2 * 16 + n;
            #pragma unroll
            for (int r = 0; r < 4; ++r)
                WbigT[(size_t)col * 768 + sgm * 256 + row0 + w * 16 + 4 * Q + r] =
                    (h16)acc4[cg2][r];
        }
    }
}

template<int OUT16RELU>
__global__ __launch_bounds__(256) void hgemm32_k(
    const h16* __restrict__ A, const h16* __restrict__ Bt,
    const float* __restrict__ bias, void* __restrict__ outv, int K, int nbp)
{
    __shared__ __align__(16) u8t lds[27648];
    const int task = blockIdx.x * 4 + blockIdx.y;
    hgemm_half(threadIdx.x, lds, task, A, Bt, bias, outv, K, nbp, OUT16RELU);
}

__global__ __launch_bounds__(512, 2) void attn_k(
    const h16* __restrict__ qb, const h16* __restrict__ kb,
    const h16* __restrict__ vbT,
    const float* __restrict__ dist, const int* __restrict__ mask,
    const float* __restrict__ tthr, const float* __restrict__ fLUT,
    h16* __restrict__ OB)
{
    const int bx = blockIdx.x, b = bx >> 5, q0 = (bx & 31) * 16;
    const int t = threadIdx.x, w = t >> 6, lane = t & 63;
    const int Q = lane >> 4, n = lane & 15;
    const int h = w;

    __shared__ __align__(16) h16 Dd[2][16][72];
    __shared__ __align__(16) u8t Cd[2][16][72];
    __shared__ __align__(16) h16 Sx[8][16][72];
    __shared__ __align__(8)  float2 lutS[8][9];

    float th[8];
    #pragma unroll
    for (int u = 0; u < 8; ++u) th[u] = tthr[u];
    if (t < 72) lutS[t & 7][t >> 3] = ((const float2*)fLUT)[t];

    const h16x8 aq =
        *(const h16x8*)(qb + ((size_t)(b * 512 + q0 + n)) * 256 + h * 32 + Q * 8);

    const f32x4 z4 = {0.f, 0.f, 0.f, 0.f};
    f32x4 acc[3][2];
    #pragma unroll
    for (int s = 0; s < 3; ++s) { acc[s][0] = z4; acc[s][1] = z4; }
    float mprev = -3e38f;
    float lsum[3] = {0.f, 0.f, 0.f};

    const int scol = lane;

    auto stage = [&](int buf, int kkb, const float* dp, const int* mp) {
        #pragma unroll
        for (int i = 0; i < 2; ++i) {
            const int row = w + 8 * i;
            const float d = dp[i];
            int idx = 0;
            #pragma unroll
            for (int u = 0; u < 8; ++u) idx += (d > th[u]) ? 1 : 0;
            const bool fr = ((q0 + row) == 0) || ((kkb + scol) == 0);
            const bool keep = (mp[i] != 0);
            const u32t code = (keep && (fr || d < 0.3f) ? 1u : 0u)
                            | (keep && (fr || d < 0.7f) ? 2u : 0u)
                            | (keep ? 4u : 0u)
                            | ((u32t)idx << 3);
            Cd[buf][row][scol] = (u8t)code;
            Dd[buf][row][scol] = (h16)d;
        }
    };

    float dv[2]; int mkv[2];
    #pragma unroll
    for (int i = 0; i < 2; ++i) {
        const size_t off = ((size_t)(b * 512 + q0 + w + 8 * i)) * 512 + scol;
        dv[i] = dist[off]; mkv[i] = mask[off];
    }
    h16x8 kf[4], vf[4];
    #pragma unroll
    for (int cg2 = 0; cg2 < 4; ++cg2)
        kf[cg2] = *(const h16x8*)(kb + ((size_t)(b * 512 + cg2 * 16 + n)) * 256 + h * 32 + Q * 8);
    #pragma unroll
    for (int nh = 0; nh < 2; ++nh)
        #pragma unroll
        for (int k2 = 0; k2 < 2; ++k2)
            vf[nh * 2 + k2] = *(const h16x8*)(
                vbT + ((size_t)((b * 8 + h) * 32 + nh * 16 + n)) * 512 + k2 * 32 + Q * 8);
    stage(0, 0, dv, mkv);
    __syncthreads();

    for (int kc = 0; kc < 8; ++kc) {
        const int cur = kc & 1, kk0 = kc * 64;

        float dN[2]; int mkN[2]; h16x8 kfN[4], vfN[4];
        if (kc < 7) {
            const int kn = kk0 + 64;
            #pragma unroll
            for (int i = 0; i < 2; ++i) {
                const size_t off = ((size_t)(b * 512 + q0 + w + 8 * i)) * 512 + kn + scol;
                dN[i] = dist[off]; mkN[i] = mask[off];
            }
            #pragma unroll
            for (int cg2 = 0; cg2 < 4; ++cg2)
                kfN[cg2] = *(const h16x8*)(
                    kb + ((size_t)(b * 512 + kn + cg2 * 16 + n)) * 256 + h * 32 + Q * 8);
            #pragma unroll
            for (int nh = 0; nh < 2; ++nh)
                #pragma unroll
                for (int k2 = 0; k2 < 2; ++k2)
                    vfN[nh * 2 + k2] = *(const h16x8*)(
                        vbT + ((size_t)((b * 8 + h) * 32 + nh * 16 + n)) * 512
                            + kn + k2 * 32 + Q * 8);
        }

        f32x4 s4[4];
        #pragma unroll
        for (int cg2 = 0; cg2 < 4; ++cg2)
            s4[cg2] = __builtin_amdgcn_mfma_f32_16x16x32_f16(aq, kf[cg2], z4, 0, 0, 0);

        #pragma unroll
        for (int cg2 = 0; cg2 < 4; ++cg2)
            #pragma unroll
            for (int r = 0; r < 4; ++r)
                Sx[w][4 * Q + r][cg2 * 16 + n] = (h16)s4[cg2][r];
        __builtin_amdgcn_wave_barrier();

        const u64t cd0 = *(const u64t*)&Cd[cur][n][Q * 8];
        const u64t cd1 = *(const u64t*)&Cd[cur][n][32 + Q * 8];
        const h16x8 dd0 = *(const h16x8*)&Dd[cur][n][Q * 8];
        const h16x8 dd1 = *(const h16x8*)&Dd[cur][n][32 + Q * 8];
        float sv[16];
        {
            h16x8 s0 = *(const h16x8*)&Sx[w][n][Q * 8];
            h16x8 s1 = *(const h16x8*)&Sx[w][n][32 + Q * 8];
            #pragma unroll
            for (int i = 0; i < 16; ++i) {
                const u32t byte = (u32t)((i < 8 ? cd0 : cd1) >> (8 * (i & 7))) & 0xFFu;
                const int idx = (int)(byte >> 3);
                const float2 se = lutS[w][idx];
                const float dfi = (float)((i < 8) ? dd0[i & 7] : dd1[i & 7]);
                const float f = fmaf(dfi, se.x, se.y);
                sv[i] = (float)((i < 8) ? s0[i & 7] : s1[i & 7]) * f;
            }
        }
        float cm = -3e38f;
        #pragma unroll
        for (int i = 0; i < 16; ++i) {
            const u32t cc = (u32t)((i < 8 ? cd0 : cd1) >> (8 * (i & 7))) & 7u;
            cm = fmaxf(cm, (cc & 4u) ? sv[i] : -3e38f);
        }
        cm = fmaxf(cm, __shfl_xor(cm, 16));
        cm = fmaxf(cm, __shfl_xor(cm, 32));
        const float mnew = fmaxf(mprev, cm);
        const float alphaA = __expf(mprev - mnew);
        mprev = mnew;

        #pragma unroll
        for (int r = 0; r < 4; ++r) {
            const float aR = __shfl(alphaA, 4 * Q + r);
            #pragma unroll
            for (int s = 0; s < 3; ++s) { acc[s][0][r] *= aR; acc[s][1][r] *= aR; }
        }

        h16x8 pf[3][2];
        float l0 = 0.f, l1 = 0.f, l2 = 0.f;
        #pragma unroll
        for (int i = 0; i < 16; ++i) {
            const u32t cc = (u32t)((i < 8 ? cd0 : cd1) >> (8 * (i & 7))) & 7u;
            const float e = __expf(sv[i] - mnew);
            const float p0 = (cc & 1u) ? e : 0.f;
            const float p1 = (cc & 2u) ? e : 0.f;
            const float p2 = (cc & 4u) ? e : 0.f;
            l0 += p0; l1 += p1; l2 += p2;
            pf[0][i >> 3][i & 7] = (h16)p0;
            pf[1][i >> 3][i & 7] = (h16)p1;
            pf[2][i >> 3][i & 7] = (h16)p2;
        }
        lsum[0] = lsum[0] * alphaA + l0;
        lsum[1] = lsum[1] * alphaA + l1;
        lsum[2] = lsum[2] * alphaA + l2;

        #pragma unroll
        for (int k2 = 0; k2 < 2; ++k2)
            #pragma unroll
            for (int nh = 0; nh < 2; ++nh)
                #pragma unroll
                for (int s = 0; s < 3; ++s)
                    acc[s][nh] = __builtin_amdgcn_mfma_f32_16x16x32_f16(
                        pf[s][k2], vf[nh * 2 + k2], acc[s][nh], 0, 0, 0);

        if (kc < 7) {
            stage(cur ^ 1, kk0 + 64, dN, mkN);
            #pragma unroll
            for (int i = 0; i < 4; ++i) { kf[i] = kfN[i]; vf[i] = vfN[i]; }
        }
        __syncthreads();
    }

    float lrow[3];
    #pragma unroll
    for (int s = 0; s < 3; ++s) {
        float lv = lsum[s];
        lv += __shfl_xor(lv, 16);
        lv += __shfl_xor(lv, 32);
        lrow[s] = lv;
    }
    #pragma unroll
    for (int s = 0; s < 3; ++s) {
        #pragma unroll
        for (int r = 0; r < 4; ++r) {
            const float il = 1.0f / __shfl(lrow[s], 4 * Q + r);
            const size_t row = (size_t)(b * 512 + q0 + 4 * Q + r);
            h16* op = OB + row * 768 + s * 256 + h * 32 + n;
            op[0]  = (h16)(acc[s][0][r] * il);
            op[16] = (h16)(acc[s][1][r] * il);
        }
    }
}

// ---------------------------------------------------------------------------
extern "C" void kernel_launch(void* const* d_in, const int* in_sizes, int n_in,
                              void* d_out, int out_size, void* d_ws, size_t ws_size,
                              hipStream_t stream)
{
    const float* query = (const float*)d_in[0];
    const float* key   = (const float*)d_in[1];
    const float* value = (const float*)d_in[2];
    const float* dist  = (const float*)d_in[3];
    const int*   mask  = (const int*)d_in[4];
    const float* Wq = (const float*)d_in[5];  const float* bq = (const float*)d_in[6];
    const float* Wk = (const float*)d_in[7];  const float* bk = (const float*)d_in[8];
    const float* Wv = (const float*)d_in[9];  const float* bv = (const float*)d_in[10];
    const float* Wo = (const float*)d_in[11]; const float* bo = (const float*)d_in[12];
    const float* cw1 = (const float*)d_in[13]; const float* cb1 = (const float*)d_in[14];
    const float* cw2 = (const float*)d_in[15]; const float* cb2 = (const float*)d_in[16];
    const float* Ws1 = (const float*)d_in[17]; const float* bs1 = (const float*)d_in[18];
    const float* Ws2 = (const float*)d_in[19]; const float* bs2 = (const float*)d_in[20];

    h16* qb    = (h16*)d_ws;            // 4096x256
    h16* kb    = qb + 1048576;          // 4096x256
    h16* vbT   = kb + 1048576;          // 64x32 x 512
    h16* OB    = vbT + 1048576;         // 4096x768 (XHx aliases this)
    h16* h1    = OB + 3145728;          // 4096x256
    h16* WT    = h1 + 1048576;          // 7 x 256x256
    h16* WbigT = WT + 458752;           // 256 x 768
    h16* XHw   = WbigT + 196608;        // Wo f16 = 65536
    float* bcombP = (float*)(XHw + 65536);     // 16 x 256
    float* tthr   = bcombP + 4096;             // 8
    float* fLUT   = tthr + 8;                  // 72 float2
    h16* XHx   = OB;                    // [Xq|Xk|Xv] f16 (prep->qkvw lifetime)

    Params prm;
    prm.Wq = Wq; prm.Wk = Wk; prm.Wv = Wv; prm.Ws2 = Ws2; prm.Ws1 = Ws1;
    prm.bo = bo; prm.bs1 = bs1;
    prm.cw1 = cw1; prm.cb1 = cb1; prm.cw2 = cw2; prm.cb2 = cb2;
    prm.Xq = query; prm.Xk = key; prm.Xv = value; prm.Wo = Wo;
    prm.bq = bq; prm.bk = bk; prm.bv = bv; prm.bs2 = bs2;
    prm.dist = dist; prm.mask = mask;
    prm.WT = WT; prm.qb = qb; prm.kb = kb; prm.vbT = vbT; prm.OB = OB;
    prm.h1 = h1; prm.WbigT = WbigT; prm.XHw = XHw; prm.XHx = XHx;
    prm.bcombP = bcombP; prm.tthr = tthr; prm.fLUT = fLUT;
    prm.outF = (float*)d_out;

    void* kargs[] = { (void*)&prm };
    hipError_t err = hipLaunchCooperativeKernel(
        (void*)mega_k, dim3(256), dim3(512), kargs, 0, stream);

    if (err != hipSuccess) {
        // fallback: proven 5-kernel pipeline
        prep_k<<<dim3(2033), 256, 0, stream>>>(Wq, Wk, Wv, Ws2, Ws1, bo, bs1,
                                               cw1, cb1, cw2, cb2,
                                               query, key, value, Wo,
                                               WT, bcombP, tthr, fLUT, XHx, XHw);
        qkvw_k<<<dim3(816), 256, 0, stream>>>(XHx, XHw, WT, bq, bk, bv,
                                              qb, kb, vbT, WbigT);
        attn_k<<<dim3(256), 512, 0, stream>>>(qb, kb, vbT, dist, mask,
                                              tthr, fLUT, OB);
        hgemm32_k<1><<<dim3(128, 4), 256, 0, stream>>>(OB, WbigT, bcombP, h1, 768, 16);
        hgemm32_k<0><<<dim3(128, 4), 256, 0, stream>>>(h1, WT + 3 * 65536, bs2, d_out, 256, 1);
    }
}

// Round 5
// 159.035 us; speedup vs baseline: 2.0998x; 2.0998x over previous
//
#include <hip/hip_runtime.h>
#include <math.h>

typedef _Float16 h16;
typedef __attribute__((ext_vector_type(4))) _Float16 h16x4;
typedef __attribute__((ext_vector_type(8))) _Float16 h16x8;
typedef __attribute__((ext_vector_type(4))) float f32x4;
typedef unsigned long long u64t;
typedef unsigned int u32t;
typedef unsigned char u8t;

// ---------------------------------------------------------------------------
// prep_k:
//   blocks 0..447  : transpose {Wq,Wk,Wv,Ws2,Ws1_0,Ws1_1,Ws1_2} f32->f16
//   blocks 448..463: bcomb partial sums (48 rows each) -> bcombP[16][256]
//   block  464     : piecewise-linear dist-conv LUT (9 intervals x 8 heads)
// ---------------------------------------------------------------------------
__global__ __launch_bounds__(256) void prep_k(
    const float* __restrict__ Wq, const float* __restrict__ Wk,
    const float* __restrict__ Wv, const float* __restrict__ Ws2,
    const float* __restrict__ Ws1, const float* __restrict__ bo,
    const float* __restrict__ bs1,
    const float* __restrict__ cw1, const float* __restrict__ cb1,
    const float* __restrict__ cw2, const float* __restrict__ cb2,
    h16* __restrict__ WT, float* __restrict__ bcombP,
    float* __restrict__ tthr, float* __restrict__ fLUT)
{
    const int bid = blockIdx.x;
    __shared__ float T[32][33];
    if (bid < 448) {
        const int z = bid >> 6, idx = bid & 63;
        const float* in = (z == 0) ? Wq : (z == 1) ? Wk : (z == 2) ? Wv :
                          (z == 3) ? Ws2 : (Ws1 + (size_t)(z - 4) * 65536);
        h16* out = WT + (size_t)z * 65536;
        const int t = threadIdx.x, tx = t & 31, ty = t >> 5;
        const int r0 = (idx >> 3) * 32, c0 = (idx & 7) * 32;
        #pragma unroll
        for (int i = 0; i < 4; ++i)
            T[ty + i * 8][tx] = in[(size_t)(r0 + ty + i * 8) * 256 + c0 + tx];
        __syncthreads();
        #pragma unroll
        for (int i = 0; i < 4; ++i)
            out[(size_t)(c0 + ty + i * 8) * 256 + r0 + tx] = (h16)T[tx][ty + i * 8];
    } else if (bid < 464) {
        // bcomb partial: rows [z*48, z*48+48)
        const int z = bid - 448;
        const int j = threadIdx.x;
        float acc = (z == 0) ? bs1[j] : 0.f;
        const int r0 = z * 48;
        #pragma unroll 4
        for (int r = r0; r < r0 + 48; ++r)
            acc = fmaf(bo[r & 255], Ws1[(size_t)r * 256 + j], acc);
        bcombP[z * 256 + j] = acc;
    } else {
        // LUT build. f_h(d) = invs*(cb2[h] + sum_u cw2[h,u]*relu(cw1[u]*d+cb1[u]))
        // piecewise linear, breakpoints t_u = -cb1[u]/cw1[u]; idx = sum_u (d > t_u).
        const int t = threadIdx.x;
        const float INVS = 0.17677669529663687f; // 1/sqrt(32)
        float tv[8]; int zu[8];
        #pragma unroll
        for (int u = 0; u < 8; ++u) {
            const float w = cw1[u];
            zu[u] = (w == 0.f) ? 1 : 0;
            tv[u] = zu[u] ? 3.0e38f : (-cb1[u] / w);
        }
        if (t < 8) tthr[t] = tv[t];
        if (t < 72) {
            const int h = t & 7, jj = t >> 3;   // jj in [0,9)
            int rank[8];
            #pragma unroll
            for (int u = 0; u < 8; ++u) {
                int rk = 0;
                #pragma unroll
                for (int v = 0; v < 8; ++v)
                    rk += ((tv[v] < tv[u]) || (tv[v] == tv[u] && v < u)) ? 1 : 0;
                rank[u] = rk;
            }
            float slope = 0.f, inter = cb2[h];
            #pragma unroll
            for (int u = 0; u < 8; ++u) {
                const float c2 = cw2[h * 8 + u];
                if (zu[u]) {
                    inter += c2 * fmaxf(cb1[u], 0.f);
                } else {
                    const bool act = (cw1[u] > 0.f) ? (rank[u] < jj) : (rank[u] >= jj);
                    if (act) {
                        slope = fmaf(c2, cw1[u], slope);
                        inter = fmaf(c2, cb1[u], inter);
                    }
                }
            }
            float2 e; e.x = INVS * slope; e.y = INVS * inter;
            ((float2*)fLUT)[jj * 8 + h] = e;
        }
    }
}

// ---------------------------------------------------------------------------
// qkvw_k: fused QKV projections (768 blocks) + Wbig = Wo @ Ws1_s (48 blocks).
// A is f32 (cvt to f16 during staging), Bt pre-transposed f16 [N][K].
// 64x64 tile, K=256, 8 iters, double-buffered, 1 barrier per k-iter.
// ---------------------------------------------------------------------------
__global__ __launch_bounds__(256) void qkvw_k(
    const float* __restrict__ Xq, const float* __restrict__ Xk,
    const float* __restrict__ Xv, const float* __restrict__ Wo,
    const h16* __restrict__ WT,
    const float* __restrict__ bq, const float* __restrict__ bk,
    const float* __restrict__ bv,
    h16* __restrict__ qb, h16* __restrict__ kb, h16* __restrict__ vbT,
    h16* __restrict__ WbigT)
{
    const int bid = blockIdx.x;
    const float* A; const h16* Bt; const float* bias = nullptr;
    int mode, row0, col0, sgm = 0;
    if (bid < 768) {
        const int z = bid >> 8, r = bid & 255;
        row0 = (r & 63) * 64; col0 = (r >> 6) * 64;
        A = (z == 0) ? Xq : (z == 1) ? Xk : Xv;
        Bt = WT + (size_t)z * 65536;
        bias = (z == 0) ? bq : (z == 1) ? bk : bv;
        mode = z;
    } else {
        const int r = bid - 768;
        sgm = r >> 4; const int tt = r & 15;
        row0 = (tt >> 2) * 64; col0 = (tt & 3) * 64;
        A = Wo; Bt = WT + (size_t)(4 + sgm) * 65536; mode = 3;
    }

    __shared__ __align__(16) h16 As[2][64][40];
    __shared__ __align__(16) h16 Bs[2][64][40];
    const int t = threadIdx.x, w = t >> 6, lane = t & 63;
    const int Q = lane >> 4, n = lane & 15;
    const int sr = t >> 2, sc = (t & 3) * 8;

    auto ldA = [&](int k0) -> h16x8 {
        const float* ap = A + (size_t)(row0 + sr) * 256 + k0 + sc;
        float4 f0 = *(const float4*)ap;
        float4 f1 = *(const float4*)(ap + 4);
        h16x8 hv;
        hv[0] = (h16)f0.x; hv[1] = (h16)f0.y; hv[2] = (h16)f0.z; hv[3] = (h16)f0.w;
        hv[4] = (h16)f1.x; hv[5] = (h16)f1.y; hv[6] = (h16)f1.z; hv[7] = (h16)f1.w;
        return hv;
    };
    auto ldB = [&](int k0) -> h16x8 {
        return *(const h16x8*)(Bt + (size_t)(col0 + sr) * 256 + k0 + sc);
    };

    {
        h16x8 a0 = ldA(0), b0 = ldB(0);
        *(h16x8*)&As[0][sr][sc] = a0;
        *(h16x8*)&Bs[0][sr][sc] = b0;
    }
    __syncthreads();

    f32x4 acc4[4];
    #pragma unroll
    for (int c = 0; c < 4; ++c) acc4[c] = (f32x4){0.f, 0.f, 0.f, 0.f};

    for (int it = 0; it < 8; ++it) {
        const int cur = it & 1;
        h16x8 arN, brN;
        if (it < 7) { arN = ldA(32 * (it + 1)); brN = ldB(32 * (it + 1)); }
        h16x8 af = *(const h16x8*)&As[cur][w * 16 + n][Q * 8];
        #pragma unroll
        for (int cg = 0; cg < 4; ++cg) {
            h16x8 bf = *(const h16x8*)&Bs[cur][cg * 16 + n][Q * 8];
            acc4[cg] = __builtin_amdgcn_mfma_f32_16x16x32_f16(af, bf, acc4[cg], 0, 0, 0);
        }
        if (it < 7) {
            *(h16x8*)&As[cur ^ 1][sr][sc] = arN;
            *(h16x8*)&Bs[cur ^ 1][sr][sc] = brN;
        }
        __syncthreads();
    }

    if (mode < 2) {
        h16* out = mode ? kb : qb;
        #pragma unroll
        for (int cg = 0; cg < 4; ++cg) {
            const float bvv = bias[col0 + cg * 16 + n];
            #pragma unroll
            for (int r = 0; r < 4; ++r)
                out[(size_t)(row0 + w * 16 + 4 * Q + r) * 256 + col0 + cg * 16 + n] =
                    (h16)(acc4[cg][r] + bvv);
        }
    } else if (mode == 2) {
        const int bb = row0 >> 9;
        #pragma unroll
        for (int cg = 0; cg < 4; ++cg) {
            const float bvv = bias[col0 + cg * 16 + n];
            const int col = col0 + cg * 16 + n;
            #pragma unroll
            for (int r = 0; r < 4; ++r) {
                const int m = row0 + w * 16 + 4 * Q + r;
                vbT[((size_t)(bb * 256 + col)) * 512 + (m & 511)] = (h16)(acc4[cg][r] + bvv);
            }
        }
    } else {
        #pragma unroll
        for (int cg = 0; cg < 4; ++cg) {
            const int col = col0 + cg * 16 + n;
            #pragma unroll
            for (int r = 0; r < 4; ++r)
                WbigT[(size_t)col * 768 + sgm * 256 + row0 + w * 16 + 4 * Q + r] =
                    (h16)acc4[cg][r];
        }
    }
}

// ---------------------------------------------------------------------------
// hgemm32_k: 32x64 tile, 256 thr, k-step 64, double-buffered single-barrier.
// Nn=256 fixed. OUT16RELU: 1 -> f16 relu(acc+bias); 0 -> f32 acc+bias.
// bias has nbp partial slices of 256 each (summed in epilogue).
// ---------------------------------------------------------------------------
template<int OUT16RELU>
__global__ __launch_bounds__(256) void hgemm32_k(
    const h16* __restrict__ A, const h16* __restrict__ Bt,
    const float* __restrict__ bias, void* __restrict__ outv, int K, int nbp)
{
    __shared__ __align__(16) h16 As[2][32][72];
    __shared__ __align__(16) h16 Bs[2][64][72];
    const int t = threadIdx.x, w = t >> 6, lane = t & 63;
    const int Q = lane >> 4, n = lane & 15;
    const int row0 = blockIdx.x * 32, col0 = blockIdx.y * 64;
    const int r16 = (w & 1) * 16, c32 = (w >> 1) * 32;
    const int asr = t >> 3, asc = (t & 7) * 8;
    const int bsr = t >> 2, bsc = (t & 3) * 16;

    auto ldA = [&](int k0) -> h16x8 {
        return *(const h16x8*)(A + (size_t)(row0 + asr) * K + k0 + asc);
    };
    auto ldB0 = [&](int k0) -> h16x8 {
        return *(const h16x8*)(Bt + (size_t)(col0 + bsr) * K + k0 + bsc);
    };
    auto ldB1 = [&](int k0) -> h16x8 {
        return *(const h16x8*)(Bt + (size_t)(col0 + bsr) * K + k0 + bsc + 8);
    };

    {
        h16x8 a0 = ldA(0), b0 = ldB0(0), b1 = ldB1(0);
        *(h16x8*)&As[0][asr][asc] = a0;
        *(h16x8*)&Bs[0][bsr][bsc] = b0;
        *(h16x8*)&Bs[0][bsr][bsc + 8] = b1;
    }
    __syncthreads();

    f32x4 acc2[2];
    acc2[0] = (f32x4){0.f, 0.f, 0.f, 0.f};
    acc2[1] = (f32x4){0.f, 0.f, 0.f, 0.f};
    const int iters = K >> 6;

    for (int it = 0; it < iters; ++it) {
        const int cur = it & 1;
        h16x8 arN, brN0, brN1;
        if (it + 1 < iters) {
            arN = ldA(64 * (it + 1));
            brN0 = ldB0(64 * (it + 1));
            brN1 = ldB1(64 * (it + 1));
        }
        #pragma unroll
        for (int kh = 0; kh < 2; ++kh) {
            h16x8 af = *(const h16x8*)&As[cur][r16 + n][kh * 32 + Q * 8];
            #pragma unroll
            for (int cg = 0; cg < 2; ++cg) {
                h16x8 bf = *(const h16x8*)&Bs[cur][c32 + cg * 16 + n][kh * 32 + Q * 8];
                acc2[cg] = __builtin_amdgcn_mfma_f32_16x16x32_f16(af, bf, acc2[cg], 0, 0, 0);
            }
        }
        if (it + 1 < iters) {
            *(h16x8*)&As[cur ^ 1][asr][asc] = arN;
            *(h16x8*)&Bs[cur ^ 1][bsr][bsc] = brN0;
            *(h16x8*)&Bs[cur ^ 1][bsr][bsc + 8] = brN1;
        }
        __syncthreads();
    }

    #pragma unroll
    for (int cg = 0; cg < 2; ++cg) {
        const int col = col0 + c32 + cg * 16 + n;
        float bv = bias[col];
        for (int p = 1; p < nbp; ++p) bv += bias[p * 256 + col];
        #pragma unroll
        for (int r = 0; r < 4; ++r) {
            const int row = row0 + r16 + 4 * Q + r;
            if (OUT16RELU)
                ((h16*)outv)[(size_t)row * 256 + col] = (h16)fmaxf(acc2[cg][r] + bv, 0.f);
            else
                ((float*)outv)[(size_t)row * 256 + col] = acc2[cg][r] + bv;
        }
    }
}

// ---------------------------------------------------------------------------
// MFMA flash attention, 3 nested scales sharing one online max.
// One 512-thread block per (b, q-tile of 16): 8 waves = 8 heads. dist/mask
// read ONCE per tile; stage stores only d (h16) + byte {code | lut_idx<<3};
// f_h(d) evaluated per-wave-head in the A-layout softmax from the LUT.
// ---------------------------------------------------------------------------
__global__ __launch_bounds__(512, 2) void attn_k(
    const h16* __restrict__ qb, const h16* __restrict__ kb,
    const h16* __restrict__ vbT,
    const float* __restrict__ dist, const int* __restrict__ mask,
    const float* __restrict__ tthr, const float* __restrict__ fLUT,
    h16* __restrict__ OB)
{
    const int bx = blockIdx.x, b = bx >> 5, q0 = (bx & 31) * 16;
    const int t = threadIdx.x, w = t >> 6, lane = t & 63;
    const int Q = lane >> 4, n = lane & 15;
    const int h = w;                       // 8 waves = 8 heads

    __shared__ __align__(16) h16 Dd[2][16][72];   // [buf][qrow][kcol] d as h16
    __shared__ __align__(16) u8t Cd[2][16][72];   // [buf][qrow][kcol] code|idx<<3
    __shared__ __align__(16) h16 Sx[8][16][72];   // per-wave raw-S transpose
    __shared__ __align__(8)  float2 lutS[8][9];   // [head][interval] slope,inter

    float th[8];
    #pragma unroll
    for (int u = 0; u < 8; ++u) th[u] = tthr[u];
    if (t < 72) lutS[t & 7][t >> 3] = ((const float2*)fLUT)[t];

    const h16x8 aq =
        *(const h16x8*)(qb + ((size_t)(b * 512 + q0 + n)) * 256 + h * 32 + Q * 8);

    const f32x4 z4 = {0.f, 0.f, 0.f, 0.f};
    f32x4 acc[3][2];
    #pragma unroll
    for (int s = 0; s < 3; ++s) { acc[s][0] = z4; acc[s][1] = z4; }
    float mprev = -3e38f;
    float lsum[3] = {0.f, 0.f, 0.f};

    const int scol = lane;   // staging: rows w, w+8; col = lane

    auto stage = [&](int buf, int kkb, const float* dp, const int* mp) {
        #pragma unroll
        for (int i = 0; i < 2; ++i) {
            const int row = w + 8 * i;
            const float d = dp[i];
            int idx = 0;
            #pragma unroll
            for (int u = 0; u < 8; ++u) idx += (d > th[u]) ? 1 : 0;
            const bool fr = ((q0 + row) == 0) || ((kkb + scol) == 0);
            const bool keep = (mp[i] != 0);
            const u32t code = (keep && (fr || d < 0.3f) ? 1u : 0u)
                            | (keep && (fr || d < 0.7f) ? 2u : 0u)
                            | (keep ? 4u : 0u)
                            | ((u32t)idx << 3);
            Cd[buf][row][scol] = (u8t)code;
            Dd[buf][row][scol] = (h16)d;
        }
    };

    // ---- prologue: chunk 0 loads + stage ----
    float dv[2]; int mkv[2];
    #pragma unroll
    for (int i = 0; i < 2; ++i) {
        const size_t off = ((size_t)(b * 512 + q0 + w + 8 * i)) * 512 + scol;
        dv[i] = dist[off]; mkv[i] = mask[off];
    }
    h16x8 kf[4], vf[4];
    #pragma unroll
    for (int cg = 0; cg < 4; ++cg)
        kf[cg] = *(const h16x8*)(kb + ((size_t)(b * 512 + cg * 16 + n)) * 256 + h * 32 + Q * 8);
    #pragma unroll
    for (int nh = 0; nh < 2; ++nh)
        #pragma unroll
        for (int k2 = 0; k2 < 2; ++k2)
            vf[nh * 2 + k2] = *(const h16x8*)(
                vbT + ((size_t)((b * 8 + h) * 32 + nh * 16 + n)) * 512 + k2 * 32 + Q * 8);
    stage(0, 0, dv, mkv);
    __syncthreads();

    for (int kc = 0; kc < 8; ++kc) {
        const int cur = kc & 1, kk0 = kc * 64;

        // ---- prefetch chunk kc+1 into regs ----
        float dN[2]; int mkN[2]; h16x8 kfN[4], vfN[4];
        if (kc < 7) {
            const int kn = kk0 + 64;
            #pragma unroll
            for (int i = 0; i < 2; ++i) {
                const size_t off = ((size_t)(b * 512 + q0 + w + 8 * i)) * 512 + kn + scol;
                dN[i] = dist[off]; mkN[i] = mask[off];
            }
            #pragma unroll
            for (int cg = 0; cg < 4; ++cg)
                kfN[cg] = *(const h16x8*)(
                    kb + ((size_t)(b * 512 + kn + cg * 16 + n)) * 256 + h * 32 + Q * 8);
            #pragma unroll
            for (int nh = 0; nh < 2; ++nh)
                #pragma unroll
                for (int k2 = 0; k2 < 2; ++k2)
                    vfN[nh * 2 + k2] = *(const h16x8*)(
                        vbT + ((size_t)((b * 8 + h) * 32 + nh * 16 + n)) * 512
                            + kn + k2 * 32 + Q * 8);
        }

        // ---- QK^T ----
        f32x4 s4[4];
        #pragma unroll
        for (int cg = 0; cg < 4; ++cg)
            s4[cg] = __builtin_amdgcn_mfma_f32_16x16x32_f16(aq, kf[cg], z4, 0, 0, 0);

        // ---- write raw S transposed ----
        #pragma unroll
        for (int cg = 0; cg < 4; ++cg)
            #pragma unroll
            for (int r = 0; r < 4; ++r)
                Sx[w][4 * Q + r][cg * 16 + n] = (h16)s4[cg][r];
        __builtin_amdgcn_wave_barrier();

        // ---- A-layout consume: f(d) apply + softmax ----
        const u64t cd0 = *(const u64t*)&Cd[cur][n][Q * 8];
        const u64t cd1 = *(const u64t*)&Cd[cur][n][32 + Q * 8];
        const h16x8 dd0 = *(const h16x8*)&Dd[cur][n][Q * 8];
        const h16x8 dd1 = *(const h16x8*)&Dd[cur][n][32 + Q * 8];
        float sv[16];
        {
            h16x8 s0 = *(const h16x8*)&Sx[w][n][Q * 8];
            h16x8 s1 = *(const h16x8*)&Sx[w][n][32 + Q * 8];
            #pragma unroll
            for (int i = 0; i < 16; ++i) {
                const u32t byte = (u32t)((i < 8 ? cd0 : cd1) >> (8 * (i & 7))) & 0xFFu;
                const int idx = (int)(byte >> 3);
                const float2 se = lutS[w][idx];
                const float dfi = (float)((i < 8) ? dd0[i & 7] : dd1[i & 7]);
                const float f = fmaf(dfi, se.x, se.y);
                sv[i] = (float)((i < 8) ? s0[i & 7] : s1[i & 7]) * f;
            }
        }
        float cm = -3e38f;
        #pragma unroll
        for (int i = 0; i < 16; ++i) {
            const u32t cc = (u32t)((i < 8 ? cd0 : cd1) >> (8 * (i & 7))) & 7u;
            cm = fmaxf(cm, (cc & 4u) ? sv[i] : -3e38f);
        }
        cm = fmaxf(cm, __shfl_xor(cm, 16));
        cm = fmaxf(cm, __shfl_xor(cm, 32));
        const float mnew = fmaxf(mprev, cm);
        const float alphaA = __expf(mprev - mnew);
        mprev = mnew;

        #pragma unroll
        for (int r = 0; r < 4; ++r) {
            const float aR = __shfl(alphaA, 4 * Q + r);
            #pragma unroll
            for (int s = 0; s < 3; ++s) { acc[s][0][r] *= aR; acc[s][1][r] *= aR; }
        }

        h16x8 pf[3][2];
        float l0 = 0.f, l1 = 0.f, l2 = 0.f;
        #pragma unroll
        for (int i = 0; i < 16; ++i) {
            const u32t cc = (u32t)((i < 8 ? cd0 : cd1) >> (8 * (i & 7))) & 7u;
            const float e = __expf(sv[i] - mnew);
            const float p0 = (cc & 1u) ? e : 0.f;
            const float p1 = (cc & 2u) ? e : 0.f;
            const float p2 = (cc & 4u) ? e : 0.f;
            l0 += p0; l1 += p1; l2 += p2;
            pf[0][i >> 3][i & 7] = (h16)p0;
            pf[1][i >> 3][i & 7] = (h16)p1;
            pf[2][i >> 3][i & 7] = (h16)p2;
        }
        lsum[0] = lsum[0] * alphaA + l0;
        lsum[1] = lsum[1] * alphaA + l1;
        lsum[2] = lsum[2] * alphaA + l2;

        // ---- P @ V ----
        #pragma unroll
        for (int k2 = 0; k2 < 2; ++k2)
            #pragma unroll
            for (int nh = 0; nh < 2; ++nh)
                #pragma unroll
                for (int s = 0; s < 3; ++s)
                    acc[s][nh] = __builtin_amdgcn_mfma_f32_16x16x32_f16(
                        pf[s][k2], vf[nh * 2 + k2], acc[s][nh], 0, 0, 0);

        // ---- stage chunk kc+1, rotate regs ----
        if (kc < 7) {
            stage(cur ^ 1, kk0 + 64, dN, mkN);
            #pragma unroll
            for (int i = 0; i < 4; ++i) { kf[i] = kfN[i]; vf[i] = vfN[i]; }
        }
        __syncthreads();
    }

    // ---- epilogue ----
    float lrow[3];
    #pragma unroll
    for (int s = 0; s < 3; ++s) {
        float lv = lsum[s];
        lv += __shfl_xor(lv, 16);
        lv += __shfl_xor(lv, 32);
        lrow[s] = lv;
    }
    #pragma unroll
    for (int s = 0; s < 3; ++s) {
        #pragma unroll
        for (int r = 0; r < 4; ++r) {
            const float il = 1.0f / __shfl(lrow[s], 4 * Q + r);
            const size_t row = (size_t)(b * 512 + q0 + 4 * Q + r);
            h16* op = OB + row * 768 + s * 256 + h * 32 + n;
            op[0]  = (h16)(acc[s][0][r] * il);
            op[16] = (h16)(acc[s][1][r] * il);
        }
    }
}

// ---------------------------------------------------------------------------
extern "C" void kernel_launch(void* const* d_in, const int* in_sizes, int n_in,
                              void* d_out, int out_size, void* d_ws, size_t ws_size,
                              hipStream_t stream)
{
    const float* query = (const float*)d_in[0];
    const float* key   = (const float*)d_in[1];
    const float* value = (const float*)d_in[2];
    const float* dist  = (const float*)d_in[3];
    const int*   mask  = (const int*)d_in[4];
    const float* Wq = (const float*)d_in[5];  const float* bq = (const float*)d_in[6];
    const float* Wk = (const float*)d_in[7];  const float* bk = (const float*)d_in[8];
    const float* Wv = (const float*)d_in[9];  const float* bv = (const float*)d_in[10];
    const float* Wo = (const float*)d_in[11]; const float* bo = (const float*)d_in[12];
    const float* cw1 = (const float*)d_in[13]; const float* cb1 = (const float*)d_in[14];
    const float* cw2 = (const float*)d_in[15]; const float* cb2 = (const float*)d_in[16];
    const float* Ws1 = (const float*)d_in[17]; const float* bs1 = (const float*)d_in[18];
    const float* Ws2 = (const float*)d_in[19]; const float* bs2 = (const float*)d_in[20];

    h16* qb    = (h16*)d_ws;            // 4096x256
    h16* kb    = qb + 1048576;          // 4096x256
    h16* vbT   = kb + 1048576;          // 64x32 x 512
    h16* OB    = vbT + 1048576;         // 4096x768
    h16* h1    = OB + 3145728;          // 4096x256
    h16* WT    = h1 + 1048576;          // 7 x 256x256
    h16* WbigT = WT + 458752;           // 256 x 768
    float* bcombP = (float*)(WbigT + 196608);  // 16 x 256
    float* tthr   = bcombP + 4096;             // 8
    float* fLUT   = tthr + 8;                  // 72 float2

    prep_k<<<dim3(465), 256, 0, stream>>>(Wq, Wk, Wv, Ws2, Ws1, bo, bs1,
                                          cw1, cb1, cw2, cb2,
                                          WT, bcombP, tthr, fLUT);

    qkvw_k<<<dim3(816), 256, 0, stream>>>(query, key, value, Wo, WT,
                                          bq, bk, bv, qb, kb, vbT, WbigT);

    attn_k<<<dim3(256), 512, 0, stream>>>(qb, kb, vbT, dist, mask,
                                          tthr, fLUT, OB);

    hgemm32_k<1><<<dim3(128, 4), 256, 0, stream>>>(OB, WbigT, bcombP, h1, 768, 16);
    hgemm32_k<0><<<dim3(128, 4), 256, 0, stream>>>(h1, WT + 3 * 65536, bs2, d_out, 256, 1);
}